// Round 3
// baseline (295.659 us; speedup 1.0000x reference)
//
#include <hip/hip_runtime.h>

#define DEV __device__ __forceinline__

typedef unsigned short u16;
typedef float  floatx4 __attribute__((ext_vector_type(4)));
typedef unsigned int uintx4 __attribute__((ext_vector_type(4)));
typedef __bf16 bf16x8 __attribute__((ext_vector_type(8)));

constexpr int cB = 4, cLQ = 1024, cLKV = 2048, cD = 1024, cH = 16, cHD = 64;

DEV u16 f2bf(float f) {
  unsigned u = __builtin_bit_cast(unsigned, f);
  u += 0x7fffu + ((u >> 16) & 1u);       // round-to-nearest-even
  return (u16)(u >> 16);
}

// truncating cvt (1 VALU op) — used only for P (positive, bias ~0.1%)
DEV u16 f2bf_t(float f) {
  return (u16)(__builtin_bit_cast(unsigned, f) >> 16);
}

DEV bf16x8 ld_frag(const u16* p) {
  uintx4 u = *(const uintx4*)p;
  return __builtin_bit_cast(bf16x8, u);
}

DEV floatx4 mfma16(bf16x8 a, bf16x8 b, floatx4 c) {
  return __builtin_amdgcn_mfma_f32_16x16x32_bf16(a, b, c, 0, 0, 0);
}

DEV float ex2(float x) { return __builtin_amdgcn_exp2f(x); }

// async global->LDS, 16 B/lane; LDS dest = wave-uniform base + lane*16
DEV void gload16(const u16* g, u16* l) {
  __builtin_amdgcn_global_load_lds(
      (const __attribute__((address_space(1))) void*)g,
      (__attribute__((address_space(3))) void*)l, 16, 0, 0);
}

// LDS-only barrier: visibility via lgkmcnt(0); does NOT drain vmcnt, so
// in-flight global prefetch loads survive across it (the m97 barrier-drain
// stall removed). Single volatile asm with memory clobber = no motion of
// any memory op across it.
#define BAR_LDS() asm volatile("s_waitcnt lgkmcnt(0)\n\ts_barrier" ::: "memory")

// ---------------------------------------------------------------------------
// prep: LN(q) rows [0,4096) + LN(kv) rows [4096,12288)  (blocks 0..12287)
//       W casts fp32->bf16                               (blocks 12288..16383)
//       lens from mask                                   (block 16384)
// ---------------------------------------------------------------------------
__global__ __launch_bounds__(256) void prep_kernel(
    const float* __restrict__ q, const float* __restrict__ kv,
    const float* __restrict__ nqw, const float* __restrict__ nqb,
    const float* __restrict__ nkw, const float* __restrict__ nkb,
    u16* __restrict__ qn, u16* __restrict__ kvn,
    const float* __restrict__ Wq, const float* __restrict__ Wkv,
    const float* __restrict__ Wo, u16* __restrict__ wqb,
    u16* __restrict__ wkvb, u16* __restrict__ wob,
    const void* __restrict__ mask, int* __restrict__ lens) {
  int bid = blockIdx.x, tid = threadIdx.x;
  if (bid < cB * (cLQ + cLKV)) {          // LayerNorm, one block per row
    const float* x; const float* w; const float* b; u16* dst;
    if (bid < cB * cLQ) {
      x = q + (size_t)bid * cD; w = nqw; b = nqb; dst = qn + (size_t)bid * cD;
    } else {
      int r2 = bid - cB * cLQ;
      x = kv + (size_t)r2 * cD; w = nkw; b = nkb; dst = kvn + (size_t)r2 * cD;
    }
    float4 v = ((const float4*)x)[tid];
    __shared__ float sbuf[8];
    float s = v.x + v.y + v.z + v.w;
    #pragma unroll
    for (int m = 1; m < 64; m <<= 1) s += __shfl_xor(s, m, 64);
    if ((tid & 63) == 0) sbuf[tid >> 6] = s;
    __syncthreads();
    float mean = (sbuf[0] + sbuf[1] + sbuf[2] + sbuf[3]) * (1.f / cD);
    float dx = v.x - mean, dy = v.y - mean, dz = v.z - mean, dw = v.w - mean;
    float ss = dx * dx + dy * dy + dz * dz + dw * dw;
    #pragma unroll
    for (int m = 1; m < 64; m <<= 1) ss += __shfl_xor(ss, m, 64);
    if ((tid & 63) == 0) sbuf[4 + (tid >> 6)] = ss;
    __syncthreads();
    float var = (sbuf[4] + sbuf[5] + sbuf[6] + sbuf[7]) * (1.f / cD);
    float rs = rsqrtf(var + 1e-5f);
    float4 wv = ((const float4*)w)[tid];
    float4 bv = ((const float4*)b)[tid];
    ushort4 o;
    o.x = f2bf(dx * rs * wv.x + bv.x);
    o.y = f2bf(dy * rs * wv.y + bv.y);
    o.z = f2bf(dz * rs * wv.z + bv.z);
    o.w = f2bf(dw * rs * wv.w + bv.w);
    ((ushort4*)dst)[tid] = o;
  } else if (bid < cB * (cLQ + cLKV) + 4096) {   // weight casts
    int gi = (bid - cB * (cLQ + cLKV)) * 256 + tid;   // quad idx 0..1M
    const float* src; u16* dst; int off;
    if (gi < 262144)      { src = Wq;  dst = wqb;  off = gi; }
    else if (gi < 786432) { src = Wkv; dst = wkvb; off = gi - 262144; }
    else                  { src = Wo;  dst = wob;  off = gi - 786432; }
    float4 v = ((const float4*)src)[off];
    ushort4 o;
    o.x = f2bf(v.x); o.y = f2bf(v.y); o.z = f2bf(v.z); o.w = f2bf(v.w);
    ((ushort4*)dst)[off] = o;
  } else {                                // lens (monotone suffix mask)
    __shared__ int smode;
    __shared__ int cnt[cB];
    if (tid == 0) smode = 0;
    if (tid < cB) cnt[tid] = 0;
    __syncthreads();
    const unsigned* mi = (const unsigned*)mask;
    int bad = 0;
    for (int i = tid; i < cB * cLKV / 4; i += 256)
      if (mi[i] > 1u) bad = 1;
    if (bad) smode = 1;
    __syncthreads();
    if (smode == 0) {                     // int32 mask
      for (int b = 0; b < cB; b++) {
        int c = 0;
        for (int i = tid; i < cLKV; i += 256) c += (mi[(size_t)b * cLKV + i] == 0u);
        atomicAdd(&cnt[b], c);
      }
    } else {                              // uint8 mask
      const unsigned char* m8 = (const unsigned char*)mask;
      for (int b = 0; b < cB; b++) {
        int c = 0;
        for (int i = tid; i < cLKV; i += 256) c += (m8[(size_t)b * cLKV + i] == 0);
        atomicAdd(&cnt[b], c);
      }
    }
    __syncthreads();
    if (tid < cB) lens[tid] = cnt[tid];
  }
}

// ---------------------------------------------------------------------------
// GEMM main loop v10: global_load_lds (async DMA, no VGPR round-trip) +
// ping-pong LDS double-buffer, ONE __syncthreads per K-iter (its vmcnt(0)
// drain is exactly the wait we need: tile i+1's staging must be complete
// before iter i+1 reads it). Stage is issued BEFORE the ds_read+MFMA phase
// so the DMA flies under compute. LDS slab per wave is linear-in-lane
// (byte = wave*1024 + lane*16), matching the HW dest rule.
// m151 A/B: this staging scheme = 874 TF vs reg-staging 646 at this tile.
// Requires K >= 64 and K % 32 == 0 (true: K=1024 at all call sites).
// ---------------------------------------------------------------------------
struct TileCtx {
  int m16, quad, wr, wc;
};

DEV void gemm_mainloop(const u16* __restrict__ A, const u16* __restrict__ Bm,
                       int row0, int col0, int K, u16* As, u16* Bs,
                       const TileCtx& t, floatx4 (&acc)[4][4]) {
  int tid = threadIdx.x;
  int wave = tid >> 6, lane = tid & 63;
  int srow = wave * 16 + (lane >> 2);     // 0..63; rounds: srow, srow+64
  int sseg = (lane & 3) * 8;
  const u16* ga = A + (size_t)(row0 + srow) * K + sseg;
  const u16* gb = Bm + (size_t)(col0 + srow) * K + sseg;
  const size_t rstep = (size_t)64 * K;
  u16* wA = As + wave * 512;              // wave-uniform LDS bases
  u16* wB = Bs + wave * 512;

  // stage tile 0 -> buf0
  gload16(ga, wA);
  gload16(ga + rstep, wA + 2048);
  gload16(gb, wB);
  gload16(gb + rstep, wB + 2048);
  __syncthreads();

  for (int k0 = 0; k0 < K; k0 += 32) {
    int cur = (k0 >> 5) & 1;
    if (k0 + 32 < K) {                    // stage tile i+1 -> buf cur^1
      int kn = k0 + 32;
      u16* nA = wA + (cur ^ 1) * 4096;
      u16* nB = wB + (cur ^ 1) * 4096;
      gload16(ga + kn, nA);
      gload16(ga + rstep + kn, nA + 2048);
      gload16(gb + kn, nB);
      gload16(gb + rstep + kn, nB + 2048);
    }
    const u16* rA = As + cur * 4096;
    const u16* rB = Bs + cur * 4096;
    bf16x8 af[4], bfr[4];
    #pragma unroll
    for (int i = 0; i < 4; i++)
      af[i] = ld_frag(&rA[(t.wr * 64 + i * 16 + t.m16) * 32 + t.quad * 8]);
    #pragma unroll
    for (int j = 0; j < 4; j++)
      bfr[j] = ld_frag(&rB[(t.wc * 64 + j * 16 + t.m16) * 32 + t.quad * 8]);
    #pragma unroll
    for (int i = 0; i < 4; i++)
      #pragma unroll
      for (int j = 0; j < 4; j++)
        acc[i][j] = mfma16(af[i], bfr[j], acc[i][j]);
    __syncthreads();
  }
}

// ---------------------------------------------------------------------------
// Fused Q-proj + KV-proj in ONE launch (1280 blocks).
//  blocks [0,256):    Q-proj -> qhb bf16 [B,LQ,H,64], x(0.125*log2e) — folds
//                     1/sqrt(HD) AND the exp->exp2 conversion for attn
//  blocks [256,1280): KV-proj -> K [b][h][kv][64], V^T [b][h][d][LKV]
// ---------------------------------------------------------------------------
__global__ __launch_bounds__(256) void proj_fused(
    const u16* __restrict__ qn, const u16* __restrict__ wqb,
    const float* __restrict__ bq, u16* __restrict__ qhb,
    const u16* __restrict__ kvn, const u16* __restrict__ wkvb,
    const float* __restrict__ bkv, u16* __restrict__ khb,
    u16* __restrict__ vthb) {
  __shared__ __align__(16) u16 As[2 * 128 * 32];
  __shared__ __align__(16) u16 Bs[2 * 128 * 32];
  int bid = blockIdx.x;
  int lane = threadIdx.x & 63;
  TileCtx t;
  t.m16 = lane & 15; t.quad = lane >> 4;
  int wave = threadIdx.x >> 6;
  t.wr = wave >> 1; t.wc = wave & 1;

  bool isQ = bid < 256;
  int row0, col0;
  const u16* A; const u16* Bm; const float* bias;
  if (isQ) {
    row0 = (bid >> 3) * 128; col0 = (bid & 7) * 128;
    A = qn; Bm = wqb; bias = bq;
  } else {
    int b2 = bid - 256;
    row0 = (b2 >> 4) * 128; col0 = (b2 & 15) * 128;
    A = kvn; Bm = wkvb; bias = bkv;
  }

  floatx4 z = {0.f, 0.f, 0.f, 0.f};
  floatx4 acc[4][4];
  #pragma unroll
  for (int i = 0; i < 4; i++)
    #pragma unroll
    for (int j = 0; j < 4; j++) acc[i][j] = z;

  gemm_mainloop(A, Bm, row0, col0, cD, As, Bs, t, acc);

  // epilogue: C/D layout col=lane&15, row=quad*4+reg
  #pragma unroll
  for (int j = 0; j < 4; j++) {
    int col = col0 + t.wc * 64 + j * 16 + t.m16;
    float bs = bias[col];
    if (isQ) {
      #pragma unroll
      for (int i = 0; i < 4; i++) {
        int crow = row0 + t.wr * 64 + i * 16 + t.quad * 4;
        #pragma unroll
        for (int r = 0; r < 4; r++)
          qhb[(size_t)(crow + r) * cD + col] =
              f2bf((acc[i][j][r] + bs) * 0.18033688f);   // 0.125 * log2(e)
      }
    } else {
      bool isK = col < cD;
      int c2 = isK ? col : col - cD;
      int hh = c2 >> 6, dd = c2 & 63;
      #pragma unroll
      for (int i = 0; i < 4; i++) {
        int crow = row0 + t.wr * 64 + i * 16 + t.quad * 4;
        int bb = crow >> 11, kvp = crow & (cLKV - 1);
        if (isK) {
          u16* dst = khb + ((size_t)(bb * cH + hh) * cLKV + kvp) * 64 + dd;
          #pragma unroll
          for (int r = 0; r < 4; r++) dst[(size_t)r * 64] = f2bf(acc[i][j][r] + bs);
        } else {
          u16* dst = vthb + ((size_t)(bb * cH + hh) * 64 + dd) * cLKV + kvp;
          ushort4 o;
          o.x = f2bf(acc[i][j][0] + bs);
          o.y = f2bf(acc[i][j][1] + bs);
          o.z = f2bf(acc[i][j][2] + bs);
          o.w = f2bf(acc[i][j][3] + bs);
          *(ushort4*)dst = o;
        }
      }
    }
  }
}

// ---------------------------------------------------------------------------
// O-proj: C f32 = aob @ Wo^T + bo + residual.
// ---------------------------------------------------------------------------
__global__ __launch_bounds__(256) void gemm_o(
    const u16* __restrict__ A, const u16* __restrict__ Bm,
    const float* __restrict__ bias, const float* __restrict__ res,
    float* __restrict__ Cout, int N, int K) {
  __shared__ __align__(16) u16 As[2 * 128 * 32];
  __shared__ __align__(16) u16 Bs[2 * 128 * 32];
  int lane = threadIdx.x & 63;
  TileCtx t;
  t.m16 = lane & 15; t.quad = lane >> 4;
  int wave = threadIdx.x >> 6;
  t.wr = wave >> 1; t.wc = wave & 1;
  int row0 = blockIdx.y * 128, col0 = blockIdx.x * 128;

  floatx4 z = {0.f, 0.f, 0.f, 0.f};
  floatx4 acc[4][4];
  #pragma unroll
  for (int i = 0; i < 4; i++)
    #pragma unroll
    for (int j = 0; j < 4; j++) acc[i][j] = z;

  gemm_mainloop(A, Bm, row0, col0, K, As, Bs, t, acc);

  #pragma unroll
  for (int j = 0; j < 4; j++) {
    int col = col0 + t.wc * 64 + j * 16 + t.m16;
    float bs = bias[col];
    #pragma unroll
    for (int i = 0; i < 4; i++) {
      int crow = row0 + t.wr * 64 + i * 16 + t.quad * 4;
      #pragma unroll
      for (int r = 0; r < 4; r++) {
        size_t idx = (size_t)(crow + r) * N + col;
        Cout[idx] = acc[i][j][r] + bs + res[idx];
      }
    }
  }
}

// ---------------------------------------------------------------------------
// Flash cross-attention v10: v9's staged skeleton + swapped-QK^T softmax,
// with both per-chunk barriers converted to LDS-only (lgkmcnt) barriers.
// The old __syncthreads drained vmcnt(0) right after the chunk-c+1 prefetch
// was issued — fully serializing the global load latency into every chunk.
// Now the prefetch stays in flight across both barriers and is waited (by
// the compiler's targeted vmcnt) only at its ds_write use, one full compute
// phase later. Barrier semantics audit: barrier#1 needs prior-chunk ds_reads
// complete (lgkmcnt covers ds ops); barrier#2 needs this chunk's ds_writes
// visible (lgkmcnt). Neither needs vmcnt. len is block-uniform, so barrier
// control flow is uniform.
// ---------------------------------------------------------------------------
constexpr int KS = 72;   // K/V LDS row stride (u16): 144 B, 16B-aligned
constexpr int PS = 72;   // P  LDS row stride (u16)

template<bool MASK>
DEV void attn_compute(int k0, int len, const u16* __restrict__ Kt,
                      const u16* __restrict__ Vt, u16* __restrict__ psw,
                      bf16x8 qf0, bf16x8 qf1, int m16, int quad,
                      float& lsum, floatx4 (&accO)[4]) {
  floatx4 z = {0.f, 0.f, 0.f, 0.f};
  // QK^T swapped: A = K (row = kv = t*16+m16, k = d), B = Q (col = q = m16)
  // D[m = kv = t*16+quad*4+r][n = q = m16]
  floatx4 s[4];
  #pragma unroll
  for (int t = 0; t < 4; t++) {
    bf16x8 kf0 = ld_frag(&Kt[(t * 16 + m16) * KS + quad * 8]);
    bf16x8 kf1 = ld_frag(&Kt[(t * 16 + m16) * KS + 32 + quad * 8]);
    floatx4 tt = z;
    tt = mfma16(kf0, qf0, tt);
    tt = mfma16(kf1, qf1, tt);
    s[t] = tt;
  }
  // exp2 + packed 8-B P-write: lane's 4 regs are CONSECUTIVE kv for q=m16
  #pragma unroll
  for (int t = 0; t < 4; t++) {
    float e0, e1, e2, e3;
    if (MASK) {
      int key = k0 + t * 16 + quad * 4;
      e0 = (key     < len) ? ex2(s[t][0]) : 0.f;
      e1 = (key + 1 < len) ? ex2(s[t][1]) : 0.f;
      e2 = (key + 2 < len) ? ex2(s[t][2]) : 0.f;
      e3 = (key + 3 < len) ? ex2(s[t][3]) : 0.f;
    } else {
      e0 = ex2(s[t][0]);
      e1 = ex2(s[t][1]);
      e2 = ex2(s[t][2]);
      e3 = ex2(s[t][3]);
    }
    lsum += (e0 + e1) + (e2 + e3);
    ushort4 pk;
    pk.x = f2bf_t(e0); pk.y = f2bf_t(e1); pk.z = f2bf_t(e2); pk.w = f2bf_t(e3);
    *(ushort4*)&psw[m16 * PS + t * 16 + quad * 4] = pk;
  }
  // PV: A = P (row = q = m16, k = kv), B = V (col = d); same-wave DS order
  bf16x8 ap0 = ld_frag(&psw[m16 * PS + quad * 8]);
  bf16x8 ap1 = ld_frag(&psw[m16 * PS + 32 + quad * 8]);
  #pragma unroll
  for (int db = 0; db < 4; db++) {
    bf16x8 bv0 = ld_frag(&Vt[(db * 16 + m16) * KS + quad * 8]);
    bf16x8 bv1 = ld_frag(&Vt[(db * 16 + m16) * KS + 32 + quad * 8]);
    accO[db] = mfma16(ap0, bv0, accO[db]);
    accO[db] = mfma16(ap1, bv1, accO[db]);
  }
}

__global__ __launch_bounds__(256) void attn_kernel(
    const u16* __restrict__ qh, const u16* __restrict__ kh,
    const u16* __restrict__ vth, const int* __restrict__ lens,
    u16* __restrict__ out) {
  int gid = blockIdx.x;
  int b = gid & (cB - 1);
  int h = (gid >> 2) & (cH - 1);
  int qt = gid >> 6;
  int len = lens[b];
  int wave = threadIdx.x >> 6, lane = threadIdx.x & 63;
  int m16 = lane & 15, quad = lane >> 4;

  __shared__ __align__(16) u16 Kt[64 * KS];
  __shared__ __align__(16) u16 Vt[64 * KS];
  __shared__ __align__(16) u16 Ps[4][16 * PS];
  u16* psw = &Ps[wave][0];

  // Q as B-operand: col = q = m16 (wave's 16 q-rows), k = d
  int qrow = qt * 64 + wave * 16 + m16;
  const u16* qp = qh + ((size_t)(b * cLQ + qrow) * cH + h) * cHD;
  bf16x8 qf0 = ld_frag(qp + quad * 8);
  bf16x8 qf1 = ld_frag(qp + 32 + quad * 8);

  const u16* kbase = kh + (size_t)(b * cH + h) * cLKV * cHD;
  const u16* vbase = vth + (size_t)(b * cH + h) * cHD * cLKV;

  int srow = threadIdx.x >> 3;   // 0..31
  int sseg = threadIdx.x & 7;    // 0..7 (16B segment)
  const u16* kg = kbase + (size_t)srow * cHD + sseg * 8;
  const u16* vg = vbase + (size_t)srow * cLKV + sseg * 8;

  float lsum = 0.f;
  floatx4 z = {0.f, 0.f, 0.f, 0.f};
  floatx4 accO[4] = {z, z, z, z};

  int nch = (len + 63) >> 6;
  // prefetch chunk 0
  uintx4 ka  = *(const uintx4*)kg;
  uintx4 kb2 = *(const uintx4*)(kg + (size_t)32 * cHD);
  uintx4 va  = *(const uintx4*)vg;
  uintx4 vb  = *(const uintx4*)(vg + (size_t)32 * cLKV);

  for (int c = 0; c < nch; c++) {
    int k0 = c * 64;
    BAR_LDS();                       // all waves done reading chunk c-1
    *(uintx4*)&Kt[srow * KS + sseg * 8] = ka;        // vmcnt wait lands here
    *(uintx4*)&Kt[(srow + 32) * KS + sseg * 8] = kb2;
    *(uintx4*)&Vt[srow * KS + sseg * 8] = va;
    *(uintx4*)&Vt[(srow + 32) * KS + sseg * 8] = vb;
    if (c + 1 < nch) {                               // prefetch chunk c+1
      int kn = k0 + 64;
      ka  = *(const uintx4*)(kg + (size_t)kn * cHD);
      kb2 = *(const uintx4*)(kg + (size_t)(kn + 32) * cHD);
      va  = *(const uintx4*)(vg + kn);
      vb  = *(const uintx4*)(vg + (size_t)32 * cLKV + kn);
    }
    BAR_LDS();                       // writes visible; prefetch NOT drained
    if (k0 + 64 <= len)
      attn_compute<false>(k0, len, Kt, Vt, psw, qf0, qf1, m16, quad, lsum, accO);
    else
      attn_compute<true>(k0, len, Kt, Vt, psw, qf0, qf1, m16, quad, lsum, accO);
  }

  // softmax denominators: lane owns q=m16 partial; reduce across quads
  float tsum = lsum;
  tsum += __shfl_xor(tsum, 16, 64);
  tsum += __shfl_xor(tsum, 32, 64);

  // epilogue: O / l, write bf16 [B,LQ,H,64]; accO rows are q = quad*4+r
  #pragma unroll
  for (int r = 0; r < 4; r++) {
    float inv = 1.0f / __shfl(tsum, quad * 4 + r, 16);
    int qg = qt * 64 + wave * 16 + quad * 4 + r;
    size_t base = ((size_t)(b * cLQ + qg) * cH + h) * cHD;
    #pragma unroll
    for (int db = 0; db < 4; db++)
      out[base + db * 16 + m16] = f2bf(accO[db][r] * inv);
  }
}

// ---------------------------------------------------------------------------
extern "C" void kernel_launch(void* const* d_in, const int* in_sizes, int n_in,
                              void* d_out, int out_size, void* d_ws, size_t ws_size,
                              hipStream_t stream) {
  const float* q    = (const float*)d_in[0];
  const float* kv   = (const float*)d_in[1];
  const void*  mask = d_in[2];
  const float* nqw  = (const float*)d_in[3];
  const float* nqb  = (const float*)d_in[4];
  const float* nkw  = (const float*)d_in[5];
  const float* nkb  = (const float*)d_in[6];
  const float* Wq   = (const float*)d_in[7];
  const float* bq   = (const float*)d_in[8];
  const float* Wkv  = (const float*)d_in[9];
  const float* bkv  = (const float*)d_in[10];
  const float* Wo   = (const float*)d_in[11];
  const float* bo   = (const float*)d_in[12];
  float* out = (float*)d_out;

  char* w = (char*)d_ws;
  int* lens = (int*)w;       w += 256;
  u16* qn   = (u16*)w;       w += (size_t)cB * cLQ * cD * 2;        // 8 MB
  u16* kvn  = (u16*)w;       w += (size_t)cB * cLKV * cD * 2;       // 16 MB
  u16* wqb  = (u16*)w;       w += (size_t)cD * cD * 2;              // 2 MB
  u16* wkvb = (u16*)w;       w += (size_t)2 * cD * cD * 2;          // 4 MB
  u16* wob  = (u16*)w;       w += (size_t)cD * cD * 2;              // 2 MB
  u16* qhb  = (u16*)w;       w += (size_t)cB * cLQ * cD * 2;        // 8 MB
  u16* khb  = (u16*)w;       w += (size_t)cB * cH * cLKV * cHD * 2; // 16 MB
  u16* vthb = (u16*)w;       w += (size_t)cB * cH * cHD * cLKV * 2; // 16 MB
  u16* aob  = (u16*)w;                                              // 8 MB

  prep_kernel<<<cB * (cLQ + cLKV) + 4096 + 1, 256, 0, stream>>>(
      q, kv, nqw, nqb, nkw, nkb, qn, kvn,
      Wq, Wkv, Wo, wqb, wkvb, wob, mask, lens);
  proj_fused<<<1280, 256, 0, stream>>>(
      qn, wqb, bq, qhb, kvn, wkvb, bkv, khb, vthb);
  attn_kernel<<<cB * cH * (cLQ / 64), 256, 0, stream>>>(
      qhb, khb, vthb, lens, aob);
  gemm_o<<<dim3(cD / 128, cB * cLQ / 128), 256, 0, stream>>>(
      aob, wob, bo, q, out, cD, cD);
}

// Round 4
// 285.848 us; speedup vs baseline: 1.0343x; 1.0343x over previous
//
#include <hip/hip_runtime.h>

#define DEV __device__ __forceinline__

typedef unsigned short u16;
typedef float  floatx4 __attribute__((ext_vector_type(4)));
typedef unsigned int uintx4 __attribute__((ext_vector_type(4)));
typedef __bf16 bf16x8 __attribute__((ext_vector_type(8)));

constexpr int cB = 4, cLQ = 1024, cLKV = 2048, cD = 1024, cH = 16, cHD = 64;

DEV u16 f2bf(float f) {
  unsigned u = __builtin_bit_cast(unsigned, f);
  u += 0x7fffu + ((u >> 16) & 1u);       // round-to-nearest-even
  return (u16)(u >> 16);
}

// truncating cvt (1 VALU op) — used only for P (positive, bias ~0.1%)
DEV u16 f2bf_t(float f) {
  return (u16)(__builtin_bit_cast(unsigned, f) >> 16);
}

DEV bf16x8 ld_frag(const u16* p) {
  uintx4 u = *(const uintx4*)p;
  return __builtin_bit_cast(bf16x8, u);
}

DEV floatx4 mfma16(bf16x8 a, bf16x8 b, floatx4 c) {
  return __builtin_amdgcn_mfma_f32_16x16x32_bf16(a, b, c, 0, 0, 0);
}

DEV float ex2(float x) { return __builtin_amdgcn_exp2f(x); }

// LDS-only barrier: visibility via lgkmcnt(0); does NOT drain vmcnt, so
// in-flight global prefetch loads (headed to VGPRs) survive across it and
// are waited only at their consuming ds_write next iter (compiler-inserted
// targeted vmcnt). Valid whenever every cross-wave obligation at the barrier
// is a DS op — true for all uses below (audited per-site).
#define BAR_LDS() asm volatile("s_waitcnt lgkmcnt(0)\n\ts_barrier" ::: "memory")

// ---------------------------------------------------------------------------
// prep: LN(q) rows [0,4096) + LN(kv) rows [4096,12288)  (blocks 0..12287)
//       W casts fp32->bf16                               (blocks 12288..16383)
//       lens from mask + len-descending batch order      (block 16384)
// ---------------------------------------------------------------------------
__global__ __launch_bounds__(256) void prep_kernel(
    const float* __restrict__ q, const float* __restrict__ kv,
    const float* __restrict__ nqw, const float* __restrict__ nqb,
    const float* __restrict__ nkw, const float* __restrict__ nkb,
    u16* __restrict__ qn, u16* __restrict__ kvn,
    const float* __restrict__ Wq, const float* __restrict__ Wkv,
    const float* __restrict__ Wo, u16* __restrict__ wqb,
    u16* __restrict__ wkvb, u16* __restrict__ wob,
    const void* __restrict__ mask, int* __restrict__ lens) {
  int bid = blockIdx.x, tid = threadIdx.x;
  if (bid < cB * (cLQ + cLKV)) {          // LayerNorm, one block per row
    const float* x; const float* w; const float* b; u16* dst;
    if (bid < cB * cLQ) {
      x = q + (size_t)bid * cD; w = nqw; b = nqb; dst = qn + (size_t)bid * cD;
    } else {
      int r2 = bid - cB * cLQ;
      x = kv + (size_t)r2 * cD; w = nkw; b = nkb; dst = kvn + (size_t)r2 * cD;
    }
    float4 v = ((const float4*)x)[tid];
    __shared__ float sbuf[8];
    float s = v.x + v.y + v.z + v.w;
    #pragma unroll
    for (int m = 1; m < 64; m <<= 1) s += __shfl_xor(s, m, 64);
    if ((tid & 63) == 0) sbuf[tid >> 6] = s;
    __syncthreads();
    float mean = (sbuf[0] + sbuf[1] + sbuf[2] + sbuf[3]) * (1.f / cD);
    float dx = v.x - mean, dy = v.y - mean, dz = v.z - mean, dw = v.w - mean;
    float ss = dx * dx + dy * dy + dz * dz + dw * dw;
    #pragma unroll
    for (int m = 1; m < 64; m <<= 1) ss += __shfl_xor(ss, m, 64);
    if ((tid & 63) == 0) sbuf[4 + (tid >> 6)] = ss;
    __syncthreads();
    float var = (sbuf[4] + sbuf[5] + sbuf[6] + sbuf[7]) * (1.f / cD);
    float rs = rsqrtf(var + 1e-5f);
    float4 wv = ((const float4*)w)[tid];
    float4 bv = ((const float4*)b)[tid];
    ushort4 o;
    o.x = f2bf(dx * rs * wv.x + bv.x);
    o.y = f2bf(dy * rs * wv.y + bv.y);
    o.z = f2bf(dz * rs * wv.z + bv.z);
    o.w = f2bf(dw * rs * wv.w + bv.w);
    ((ushort4*)dst)[tid] = o;
  } else if (bid < cB * (cLQ + cLKV) + 4096) {   // weight casts
    int gi = (bid - cB * (cLQ + cLKV)) * 256 + tid;   // quad idx 0..1M
    const float* src; u16* dst; int off;
    if (gi < 262144)      { src = Wq;  dst = wqb;  off = gi; }
    else if (gi < 786432) { src = Wkv; dst = wkvb; off = gi - 262144; }
    else                  { src = Wo;  dst = wob;  off = gi - 786432; }
    float4 v = ((const float4*)src)[off];
    ushort4 o;
    o.x = f2bf(v.x); o.y = f2bf(v.y); o.z = f2bf(v.z); o.w = f2bf(v.w);
    ((ushort4*)dst)[off] = o;
  } else {                                // lens (monotone suffix mask)
    __shared__ int smode;
    __shared__ int cnt[cB];
    if (tid == 0) smode = 0;
    if (tid < cB) cnt[tid] = 0;
    __syncthreads();
    const unsigned* mi = (const unsigned*)mask;
    int bad = 0;
    for (int i = tid; i < cB * cLKV / 4; i += 256)
      if (mi[i] > 1u) bad = 1;
    if (bad) smode = 1;
    __syncthreads();
    if (smode == 0) {                     // int32 mask
      for (int b = 0; b < cB; b++) {
        int c = 0;
        for (int i = tid; i < cLKV; i += 256) c += (mi[(size_t)b * cLKV + i] == 0u);
        atomicAdd(&cnt[b], c);
      }
    } else {                              // uint8 mask
      const unsigned char* m8 = (const unsigned char*)mask;
      for (int b = 0; b < cB; b++) {
        int c = 0;
        for (int i = tid; i < cLKV; i += 256) c += (m8[(size_t)b * cLKV + i] == 0);
        atomicAdd(&cnt[b], c);
      }
    }
    __syncthreads();
    if (tid < cB) lens[tid] = cnt[tid];
    if (tid == 0) {                       // order[4] = batches, len-descending
      int ord[4] = {0, 1, 2, 3};
      #pragma unroll
      for (int a = 0; a < 3; a++)
        #pragma unroll
        for (int d = 0; d < 3; d++)
          if (cnt[ord[d]] < cnt[ord[d + 1]]) {
            int tswap = ord[d]; ord[d] = ord[d + 1]; ord[d + 1] = tswap;
          }
      #pragma unroll
      for (int a = 0; a < 4; a++) lens[4 + a] = ord[a];
    }
  }
}

// ---------------------------------------------------------------------------
// GEMM main loop v11: v9's proven reg-staging ping-pong (645 TF) with the
// per-iter barrier converted to LDS-only. v9's __syncthreads sat immediately
// after the global prefetch issue, so its vmcnt(0) drain serialized the L2
// latency of the prefetch into every K-iter. BAR_LDS keeps all cross-wave
// obligations (they are all DS ops: reads of buf[cur] drained, writes of
// buf[cur^1] visible) while the prefetch stays in flight until its ds_write
// next iter. v10's global_load_lds path REVERTED (measured -13%: one-barrier
// loop gives the DMA only one compute phase of slack + full-block drain).
// Requires K >= 64 and K % 32 == 0 (true: K=1024 at all call sites).
// ---------------------------------------------------------------------------
struct TileCtx {
  int m16, quad, wr, wc;
};

DEV void gemm_mainloop(const u16* __restrict__ A, const u16* __restrict__ Bm,
                       int row0, int col0, int K, u16* As, u16* Bs,
                       const TileCtx& t, floatx4 (&acc)[4][4]) {
  int tid = threadIdx.x;
  int wave = tid >> 6, lane = tid & 63;
  int srow = wave * 16 + (lane >> 2);     // 0..63; rounds: srow, srow+64
  int sseg = (lane & 3) * 8;
  const u16* ga = A + (size_t)(row0 + srow) * K + sseg;
  const u16* gb = Bm + (size_t)(col0 + srow) * K + sseg;
  const size_t rstep = (size_t)64 * K;
  int woff = srow * 32 + sseg;

  // tile 0 -> buf0
  uintx4 a0 = *(const uintx4*)ga;
  uintx4 a1 = *(const uintx4*)(ga + rstep);
  uintx4 b0 = *(const uintx4*)gb;
  uintx4 b1 = *(const uintx4*)(gb + rstep);
  *(uintx4*)(As + woff) = a0;
  *(uintx4*)(As + woff + 2048) = a1;
  *(uintx4*)(Bs + woff) = b0;
  *(uintx4*)(Bs + woff + 2048) = b1;
  // prefetch tile 1 (in flight across BAR_LDS)
  a0 = *(const uintx4*)(ga + 32);
  a1 = *(const uintx4*)(ga + rstep + 32);
  b0 = *(const uintx4*)(gb + 32);
  b1 = *(const uintx4*)(gb + rstep + 32);
  BAR_LDS();

  for (int k0 = 0; k0 < K; k0 += 32) {
    int cur = (k0 >> 5) & 1;
    const u16* rA = As + cur * 4096;
    const u16* rB = Bs + cur * 4096;
    bf16x8 af[4], bfr[4];
    #pragma unroll
    for (int i = 0; i < 4; i++)
      af[i] = ld_frag(&rA[(t.wr * 64 + i * 16 + t.m16) * 32 + t.quad * 8]);
    #pragma unroll
    for (int j = 0; j < 4; j++)
      bfr[j] = ld_frag(&rB[(t.wc * 64 + j * 16 + t.m16) * 32 + t.quad * 8]);
    if (k0 + 32 < K) {                    // stage next tile into other buffer
      u16* nA = As + (cur ^ 1) * 4096 + woff;
      u16* nB = Bs + (cur ^ 1) * 4096 + woff;
      *(uintx4*)nA = a0;                  // targeted vmcnt wait lands here
      *(uintx4*)(nA + 2048) = a1;
      *(uintx4*)nB = b0;
      *(uintx4*)(nB + 2048) = b1;
      if (k0 + 64 < K) {                  // prefetch tile k0+64
        a0 = *(const uintx4*)(ga + k0 + 64);
        a1 = *(const uintx4*)(ga + rstep + k0 + 64);
        b0 = *(const uintx4*)(gb + k0 + 64);
        b1 = *(const uintx4*)(gb + rstep + k0 + 64);
      }
    }
    #pragma unroll
    for (int i = 0; i < 4; i++)
      #pragma unroll
      for (int j = 0; j < 4; j++)
        acc[i][j] = mfma16(af[i], bfr[j], acc[i][j]);
    BAR_LDS();   // reads of buf[cur] drained; writes of buf[cur^1] visible;
                 // prefetch for tile k0+64 NOT drained (vmcnt untouched)
  }
}

// ---------------------------------------------------------------------------
// Fused Q-proj + KV-proj in ONE launch (1280 blocks).
//  blocks [0,256):    Q-proj -> qhb bf16 [B,LQ,H,64], x(0.125*log2e) — folds
//                     1/sqrt(HD) AND the exp->exp2 conversion for attn
//  blocks [256,1280): KV-proj -> K [b][h][kv][64], V^T [b][h][d][LKV]
// ---------------------------------------------------------------------------
__global__ __launch_bounds__(256) void proj_fused(
    const u16* __restrict__ qn, const u16* __restrict__ wqb,
    const float* __restrict__ bq, u16* __restrict__ qhb,
    const u16* __restrict__ kvn, const u16* __restrict__ wkvb,
    const float* __restrict__ bkv, u16* __restrict__ khb,
    u16* __restrict__ vthb) {
  __shared__ __align__(16) u16 As[2 * 128 * 32];
  __shared__ __align__(16) u16 Bs[2 * 128 * 32];
  int bid = blockIdx.x;
  int lane = threadIdx.x & 63;
  TileCtx t;
  t.m16 = lane & 15; t.quad = lane >> 4;
  int wave = threadIdx.x >> 6;
  t.wr = wave >> 1; t.wc = wave & 1;

  bool isQ = bid < 256;
  int row0, col0;
  const u16* A; const u16* Bm; const float* bias;
  if (isQ) {
    row0 = (bid >> 3) * 128; col0 = (bid & 7) * 128;
    A = qn; Bm = wqb; bias = bq;
  } else {
    int b2 = bid - 256;
    row0 = (b2 >> 4) * 128; col0 = (b2 & 15) * 128;
    A = kvn; Bm = wkvb; bias = bkv;
  }

  floatx4 z = {0.f, 0.f, 0.f, 0.f};
  floatx4 acc[4][4];
  #pragma unroll
  for (int i = 0; i < 4; i++)
    #pragma unroll
    for (int j = 0; j < 4; j++) acc[i][j] = z;

  gemm_mainloop(A, Bm, row0, col0, cD, As, Bs, t, acc);

  // epilogue: C/D layout col=lane&15, row=quad*4+reg
  #pragma unroll
  for (int j = 0; j < 4; j++) {
    int col = col0 + t.wc * 64 + j * 16 + t.m16;
    float bs = bias[col];
    if (isQ) {
      #pragma unroll
      for (int i = 0; i < 4; i++) {
        int crow = row0 + t.wr * 64 + i * 16 + t.quad * 4;
        #pragma unroll
        for (int r = 0; r < 4; r++)
          qhb[(size_t)(crow + r) * cD + col] =
              f2bf((acc[i][j][r] + bs) * 0.18033688f);   // 0.125 * log2(e)
      }
    } else {
      bool isK = col < cD;
      int c2 = isK ? col : col - cD;
      int hh = c2 >> 6, dd = c2 & 63;
      #pragma unroll
      for (int i = 0; i < 4; i++) {
        int crow = row0 + t.wr * 64 + i * 16 + t.quad * 4;
        int bb = crow >> 11, kvp = crow & (cLKV - 1);
        if (isK) {
          u16* dst = khb + ((size_t)(bb * cH + hh) * cLKV + kvp) * 64 + dd;
          #pragma unroll
          for (int r = 0; r < 4; r++) dst[(size_t)r * 64] = f2bf(acc[i][j][r] + bs);
        } else {
          u16* dst = vthb + ((size_t)(bb * cH + hh) * 64 + dd) * cLKV + kvp;
          ushort4 o;
          o.x = f2bf(acc[i][j][0] + bs);
          o.y = f2bf(acc[i][j][1] + bs);
          o.z = f2bf(acc[i][j][2] + bs);
          o.w = f2bf(acc[i][j][3] + bs);
          *(ushort4*)dst = o;
        }
      }
    }
  }
}

// ---------------------------------------------------------------------------
// O-proj: C f32 = aob @ Wo^T + bo + residual.
// ---------------------------------------------------------------------------
__global__ __launch_bounds__(256) void gemm_o(
    const u16* __restrict__ A, const u16* __restrict__ Bm,
    const float* __restrict__ bias, const float* __restrict__ res,
    float* __restrict__ Cout, int N, int K) {
  __shared__ __align__(16) u16 As[2 * 128 * 32];
  __shared__ __align__(16) u16 Bs[2 * 128 * 32];
  int lane = threadIdx.x & 63;
  TileCtx t;
  t.m16 = lane & 15; t.quad = lane >> 4;
  int wave = threadIdx.x >> 6;
  t.wr = wave >> 1; t.wc = wave & 1;
  int row0 = blockIdx.y * 128, col0 = blockIdx.x * 128;

  floatx4 z = {0.f, 0.f, 0.f, 0.f};
  floatx4 acc[4][4];
  #pragma unroll
  for (int i = 0; i < 4; i++)
    #pragma unroll
    for (int j = 0; j < 4; j++) acc[i][j] = z;

  gemm_mainloop(A, Bm, row0, col0, K, As, Bs, t, acc);

  #pragma unroll
  for (int j = 0; j < 4; j++) {
    int col = col0 + t.wc * 64 + j * 16 + t.m16;
    float bs = bias[col];
    #pragma unroll
    for (int i = 0; i < 4; i++) {
      int crow = row0 + t.wr * 64 + i * 16 + t.quad * 4;
      #pragma unroll
      for (int r = 0; r < 4; r++) {
        size_t idx = (size_t)(crow + r) * N + col;
        Cout[idx] = acc[i][j][r] + bs + res[idx];
      }
    }
  }
}

// ---------------------------------------------------------------------------
// Flash cross-attention v11: swapped-QK^T softmax path (v9) + ping-pong
// double-buffered K/V LDS with ONE lgkm-barrier per chunk (was 2).
// Hazard audit for the single barrier at end of iter c (p = c&1):
//   - iter c reads Kt[p]/Vt[p]: written in iter c-1 before its end barrier
//     (lgkmcnt(0) completes ds_writes) -> visible. OK.
//   - iter c writes Kt[p^1]/Vt[p^1]: iter c-1 read those buffers; a wave
//     enters iter c only after ALL waves passed the c-1 barrier, and each
//     wave's reads completed before it arrived (lgkmcnt(0)). OK.
//   - global prefetch for chunk c+2 is issued before the barrier and NOT
//     drained (BAR_LDS leaves vmcnt alone); its targeted wait lands at the
//     ds_write in iter c+1, a full chunk later.
// Compute runs FIRST in each iter (no dependence on this iter's staging),
// then staged writes + next prefetch. Block order: b = order[gid&3] with
// order len-descending (prep) so long-len blocks launch first (tail trim).
// LDS = 2*18432 (K,V) + 9216 (P) = 46080 B -> 3 blocks/CU.
// ---------------------------------------------------------------------------
constexpr int KS = 72;   // K/V LDS row stride (u16): 144 B, 16B-aligned
constexpr int PS = 72;   // P  LDS row stride (u16)

template<bool MASK>
DEV void attn_compute(int k0, int len, const u16* __restrict__ Kt,
                      const u16* __restrict__ Vt, u16* __restrict__ psw,
                      bf16x8 qf0, bf16x8 qf1, int m16, int quad,
                      float& lsum, floatx4 (&accO)[4]) {
  floatx4 z = {0.f, 0.f, 0.f, 0.f};
  // QK^T swapped: A = K (row = kv = t*16+m16, k = d), B = Q (col = q = m16)
  // D[m = kv = t*16+quad*4+r][n = q = m16]
  floatx4 s[4];
  #pragma unroll
  for (int t = 0; t < 4; t++) {
    bf16x8 kf0 = ld_frag(&Kt[(t * 16 + m16) * KS + quad * 8]);
    bf16x8 kf1 = ld_frag(&Kt[(t * 16 + m16) * KS + 32 + quad * 8]);
    floatx4 tt = z;
    tt = mfma16(kf0, qf0, tt);
    tt = mfma16(kf1, qf1, tt);
    s[t] = tt;
  }
  // exp2 + packed 8-B P-write: lane's 4 regs are CONSECUTIVE kv for q=m16
  #pragma unroll
  for (int t = 0; t < 4; t++) {
    float e0, e1, e2, e3;
    if (MASK) {
      int key = k0 + t * 16 + quad * 4;
      e0 = (key     < len) ? ex2(s[t][0]) : 0.f;
      e1 = (key + 1 < len) ? ex2(s[t][1]) : 0.f;
      e2 = (key + 2 < len) ? ex2(s[t][2]) : 0.f;
      e3 = (key + 3 < len) ? ex2(s[t][3]) : 0.f;
    } else {
      e0 = ex2(s[t][0]);
      e1 = ex2(s[t][1]);
      e2 = ex2(s[t][2]);
      e3 = ex2(s[t][3]);
    }
    lsum += (e0 + e1) + (e2 + e3);
    ushort4 pk;
    pk.x = f2bf_t(e0); pk.y = f2bf_t(e1); pk.z = f2bf_t(e2); pk.w = f2bf_t(e3);
    *(ushort4*)&psw[m16 * PS + t * 16 + quad * 4] = pk;
  }
  // PV: A = P (row = q = m16, k = kv), B = V (col = d); same-wave DS order
  bf16x8 ap0 = ld_frag(&psw[m16 * PS + quad * 8]);
  bf16x8 ap1 = ld_frag(&psw[m16 * PS + 32 + quad * 8]);
  #pragma unroll
  for (int db = 0; db < 4; db++) {
    bf16x8 bv0 = ld_frag(&Vt[(db * 16 + m16) * KS + quad * 8]);
    bf16x8 bv1 = ld_frag(&Vt[(db * 16 + m16) * KS + 32 + quad * 8]);
    accO[db] = mfma16(ap0, bv0, accO[db]);
    accO[db] = mfma16(ap1, bv1, accO[db]);
  }
}

__global__ __launch_bounds__(256) void attn_kernel(
    const u16* __restrict__ qh, const u16* __restrict__ kh,
    const u16* __restrict__ vth, const int* __restrict__ lens,
    u16* __restrict__ out) {
  int gid = blockIdx.x;
  int b = lens[4 + (gid & (cB - 1))];     // len-descending batch order
  int h = (gid >> 2) & (cH - 1);
  int qt = gid >> 6;
  int len = lens[b];
  int wave = threadIdx.x >> 6, lane = threadIdx.x & 63;
  int m16 = lane & 15, quad = lane >> 4;

  __shared__ __align__(16) u16 Kt[2][64 * KS];
  __shared__ __align__(16) u16 Vt[2][64 * KS];
  __shared__ __align__(16) u16 Ps[4][16 * PS];
  u16* psw = &Ps[wave][0];

  // Q as B-operand: col = q = m16 (wave's 16 q-rows), k = d
  int qrow = qt * 64 + wave * 16 + m16;
  const u16* qp = qh + ((size_t)(b * cLQ + qrow) * cH + h) * cHD;
  bf16x8 qf0 = ld_frag(qp + quad * 8);
  bf16x8 qf1 = ld_frag(qp + 32 + quad * 8);

  const u16* kbase = kh + (size_t)(b * cH + h) * cLKV * cHD;
  const u16* vbase = vth + (size_t)(b * cH + h) * cHD * cLKV;

  int srow = threadIdx.x >> 3;   // 0..31
  int sseg = threadIdx.x & 7;    // 0..7 (16B segment)
  const u16* kg = kbase + (size_t)srow * cHD + sseg * 8;
  const u16* vg = vbase + (size_t)srow * cLKV + sseg * 8;

  float lsum = 0.f;
  floatx4 z = {0.f, 0.f, 0.f, 0.f};
  floatx4 accO[4] = {z, z, z, z};

  int nch = (len + 63) >> 6;
  // chunk 0 -> buf0 (direct), prefetch chunk 1 into VGPRs
  {
    uintx4 k0a = *(const uintx4*)kg;
    uintx4 k0b = *(const uintx4*)(kg + (size_t)32 * cHD);
    uintx4 v0a = *(const uintx4*)vg;
    uintx4 v0b = *(const uintx4*)(vg + (size_t)32 * cLKV);
    *(uintx4*)&Kt[0][srow * KS + sseg * 8] = k0a;
    *(uintx4*)&Kt[0][(srow + 32) * KS + sseg * 8] = k0b;
    *(uintx4*)&Vt[0][srow * KS + sseg * 8] = v0a;
    *(uintx4*)&Vt[0][(srow + 32) * KS + sseg * 8] = v0b;
  }
  uintx4 ka, kb2, va, vb;
  if (nch > 1) {
    ka  = *(const uintx4*)(kg + (size_t)64 * cHD);
    kb2 = *(const uintx4*)(kg + (size_t)96 * cHD);
    va  = *(const uintx4*)(vg + 64);
    vb  = *(const uintx4*)(vg + (size_t)32 * cLKV + 64);
  }
  BAR_LDS();   // chunk-0 writes visible; chunk-1 prefetch stays in flight

  for (int c = 0; c < nch; c++) {
    int k0 = c * 64;
    int p = c & 1;
    if (k0 + 64 <= len)
      attn_compute<false>(k0, len, Kt[p], Vt[p], psw, qf0, qf1, m16, quad, lsum, accO);
    else
      attn_compute<true>(k0, len, Kt[p], Vt[p], psw, qf0, qf1, m16, quad, lsum, accO);
    if (c + 1 < nch) {
      // staged chunk c+1 -> other buffer (targeted vmcnt wait lands here)
      *(uintx4*)&Kt[p ^ 1][srow * KS + sseg * 8] = ka;
      *(uintx4*)&Kt[p ^ 1][(srow + 32) * KS + sseg * 8] = kb2;
      *(uintx4*)&Vt[p ^ 1][srow * KS + sseg * 8] = va;
      *(uintx4*)&Vt[p ^ 1][(srow + 32) * KS + sseg * 8] = vb;
      if (c + 2 < nch) {                  // prefetch chunk c+2
        int kn = k0 + 128;
        ka  = *(const uintx4*)(kg + (size_t)kn * cHD);
        kb2 = *(const uintx4*)(kg + (size_t)(kn + 32) * cHD);
        va  = *(const uintx4*)(vg + kn);
        vb  = *(const uintx4*)(vg + (size_t)32 * cLKV + kn);
      }
    }
    BAR_LDS();   // single barrier per chunk (audit in header comment)
  }

  // softmax denominators: lane owns q=m16 partial; reduce across quads
  float tsum = lsum;
  tsum += __shfl_xor(tsum, 16, 64);
  tsum += __shfl_xor(tsum, 32, 64);

  // epilogue: O / l, write bf16 [B,LQ,H,64]; accO rows are q = quad*4+r
  #pragma unroll
  for (int r = 0; r < 4; r++) {
    float inv = 1.0f / __shfl(tsum, quad * 4 + r, 16);
    int qg = qt * 64 + wave * 16 + quad * 4 + r;
    size_t base = ((size_t)(b * cLQ + qg) * cH + h) * cHD;
    #pragma unroll
    for (int db = 0; db < 4; db++)
      out[base + db * 16 + m16] = f2bf(accO[db][r] * inv);
  }
}

// ---------------------------------------------------------------------------
extern "C" void kernel_launch(void* const* d_in, const int* in_sizes, int n_in,
                              void* d_out, int out_size, void* d_ws, size_t ws_size,
                              hipStream_t stream) {
  const float* q    = (const float*)d_in[0];
  const float* kv   = (const float*)d_in[1];
  const void*  mask = d_in[2];
  const float* nqw  = (const float*)d_in[3];
  const float* nqb  = (const float*)d_in[4];
  const float* nkw  = (const float*)d_in[5];
  const float* nkb  = (const float*)d_in[6];
  const float* Wq   = (const float*)d_in[7];
  const float* bq   = (const float*)d_in[8];
  const float* Wkv  = (const float*)d_in[9];
  const float* bkv  = (const float*)d_in[10];
  const float* Wo   = (const float*)d_in[11];
  const float* bo   = (const float*)d_in[12];
  float* out = (float*)d_out;

  char* w = (char*)d_ws;
  int* lens = (int*)w;       w += 256;
  u16* qn   = (u16*)w;       w += (size_t)cB * cLQ * cD * 2;        // 8 MB
  u16* kvn  = (u16*)w;       w += (size_t)cB * cLKV * cD * 2;       // 16 MB
  u16* wqb  = (u16*)w;       w += (size_t)cD * cD * 2;              // 2 MB
  u16* wkvb = (u16*)w;       w += (size_t)2 * cD * cD * 2;          // 4 MB
  u16* wob  = (u16*)w;       w += (size_t)cD * cD * 2;              // 2 MB
  u16* qhb  = (u16*)w;       w += (size_t)cB * cLQ * cD * 2;        // 8 MB
  u16* khb  = (u16*)w;       w += (size_t)cB * cH * cLKV * cHD * 2; // 16 MB
  u16* vthb = (u16*)w;       w += (size_t)cB * cH * cHD * cLKV * 2; // 16 MB
  u16* aob  = (u16*)w;                                              // 8 MB

  prep_kernel<<<cB * (cLQ + cLKV) + 4096 + 1, 256, 0, stream>>>(
      q, kv, nqw, nqb, nkw, nkb, qn, kvn,
      Wq, Wkv, Wo, wqb, wkvb, wob, mask, lens);
  proj_fused<<<1280, 256, 0, stream>>>(
      qn, wqb, bq, qhb, kvn, wkvb, bkv, khb, vthb);
  attn_kernel<<<cB * cH * (cLQ / 64), 256, 0, stream>>>(
      qhb, khb, vthb, lens, aob);
  gemm_o<<<dim3(cD / 128, cB * cLQ / 128), 256, 0, stream>>>(
      aob, wob, bo, q, out, cD, cD);
}

// Round 5
// 262.049 us; speedup vs baseline: 1.1283x; 1.0908x over previous
//
#include <hip/hip_runtime.h>

#define DEV __device__ __forceinline__

typedef unsigned short u16;
typedef float  floatx4 __attribute__((ext_vector_type(4)));
typedef unsigned int uintx4 __attribute__((ext_vector_type(4)));
typedef __bf16 bf16x8 __attribute__((ext_vector_type(8)));

constexpr int cB = 4, cLQ = 1024, cLKV = 2048, cD = 1024, cH = 16, cHD = 64;

DEV u16 f2bf(float f) {
  unsigned u = __builtin_bit_cast(unsigned, f);
  u += 0x7fffu + ((u >> 16) & 1u);       // round-to-nearest-even
  return (u16)(u >> 16);
}

// truncating cvt (1 VALU op) — used only for P (positive, bias ~0.1%)
DEV u16 f2bf_t(float f) {
  return (u16)(__builtin_bit_cast(unsigned, f) >> 16);
}

DEV bf16x8 ld_frag(const u16* p) {
  uintx4 u = *(const uintx4*)p;
  return __builtin_bit_cast(bf16x8, u);
}

DEV floatx4 mfma16(bf16x8 a, bf16x8 b, floatx4 c) {
  return __builtin_amdgcn_mfma_f32_16x16x32_bf16(a, b, c, 0, 0, 0);
}

DEV float ex2(float x) { return __builtin_amdgcn_exp2f(x); }

// ---------------------------------------------------------------------------
// prep: LN(q) rows [0,4096) + LN(kv) rows [4096,12288)  (blocks 0..12287)
//       W casts fp32->bf16                               (blocks 12288..16383)
//       lens from mask + len-descending batch order      (block 16384)
// ---------------------------------------------------------------------------
__global__ __launch_bounds__(256) void prep_kernel(
    const float* __restrict__ q, const float* __restrict__ kv,
    const float* __restrict__ nqw, const float* __restrict__ nqb,
    const float* __restrict__ nkw, const float* __restrict__ nkb,
    u16* __restrict__ qn, u16* __restrict__ kvn,
    const float* __restrict__ Wq, const float* __restrict__ Wkv,
    const float* __restrict__ Wo, u16* __restrict__ wqb,
    u16* __restrict__ wkvb, u16* __restrict__ wob,
    const void* __restrict__ mask, int* __restrict__ lens) {
  int bid = blockIdx.x, tid = threadIdx.x;
  if (bid < cB * (cLQ + cLKV)) {          // LayerNorm, one block per row
    const float* x; const float* w; const float* b; u16* dst;
    if (bid < cB * cLQ) {
      x = q + (size_t)bid * cD; w = nqw; b = nqb; dst = qn + (size_t)bid * cD;
    } else {
      int r2 = bid - cB * cLQ;
      x = kv + (size_t)r2 * cD; w = nkw; b = nkb; dst = kvn + (size_t)r2 * cD;
    }
    float4 v = ((const float4*)x)[tid];
    __shared__ float sbuf[8];
    float s = v.x + v.y + v.z + v.w;
    #pragma unroll
    for (int m = 1; m < 64; m <<= 1) s += __shfl_xor(s, m, 64);
    if ((tid & 63) == 0) sbuf[tid >> 6] = s;
    __syncthreads();
    float mean = (sbuf[0] + sbuf[1] + sbuf[2] + sbuf[3]) * (1.f / cD);
    float dx = v.x - mean, dy = v.y - mean, dz = v.z - mean, dw = v.w - mean;
    float ss = dx * dx + dy * dy + dz * dz + dw * dw;
    #pragma unroll
    for (int m = 1; m < 64; m <<= 1) ss += __shfl_xor(ss, m, 64);
    if ((tid & 63) == 0) sbuf[4 + (tid >> 6)] = ss;
    __syncthreads();
    float var = (sbuf[4] + sbuf[5] + sbuf[6] + sbuf[7]) * (1.f / cD);
    float rs = rsqrtf(var + 1e-5f);
    float4 wv = ((const float4*)w)[tid];
    float4 bv = ((const float4*)b)[tid];
    ushort4 o;
    o.x = f2bf(dx * rs * wv.x + bv.x);
    o.y = f2bf(dy * rs * wv.y + bv.y);
    o.z = f2bf(dz * rs * wv.z + bv.z);
    o.w = f2bf(dw * rs * wv.w + bv.w);
    ((ushort4*)dst)[tid] = o;
  } else if (bid < cB * (cLQ + cLKV) + 4096) {   // weight casts
    int gi = (bid - cB * (cLQ + cLKV)) * 256 + tid;   // quad idx 0..1M
    const float* src; u16* dst; int off;
    if (gi < 262144)      { src = Wq;  dst = wqb;  off = gi; }
    else if (gi < 786432) { src = Wkv; dst = wkvb; off = gi - 262144; }
    else                  { src = Wo;  dst = wob;  off = gi - 786432; }
    float4 v = ((const float4*)src)[off];
    ushort4 o;
    o.x = f2bf(v.x); o.y = f2bf(v.y); o.z = f2bf(v.z); o.w = f2bf(v.w);
    ((ushort4*)dst)[off] = o;
  } else {                                // lens (monotone suffix mask)
    __shared__ int smode;
    __shared__ int cnt[cB];
    if (tid == 0) smode = 0;
    if (tid < cB) cnt[tid] = 0;
    __syncthreads();
    const unsigned* mi = (const unsigned*)mask;
    int bad = 0;
    for (int i = tid; i < cB * cLKV / 4; i += 256)
      if (mi[i] > 1u) bad = 1;
    if (bad) smode = 1;
    __syncthreads();
    if (smode == 0) {                     // int32 mask
      for (int b = 0; b < cB; b++) {
        int c = 0;
        for (int i = tid; i < cLKV; i += 256) c += (mi[(size_t)b * cLKV + i] == 0u);
        atomicAdd(&cnt[b], c);
      }
    } else {                              // uint8 mask
      const unsigned char* m8 = (const unsigned char*)mask;
      for (int b = 0; b < cB; b++) {
        int c = 0;
        for (int i = tid; i < cLKV; i += 256) c += (m8[(size_t)b * cLKV + i] == 0);
        atomicAdd(&cnt[b], c);
      }
    }
    __syncthreads();
    if (tid < cB) lens[tid] = cnt[tid];
    if (tid == 0) {                       // order[4] = batches, len-descending
      int ord[4] = {0, 1, 2, 3};
      #pragma unroll
      for (int a = 0; a < 3; a++)
        #pragma unroll
        for (int d = 0; d < 3; d++)
          if (cnt[ord[d]] < cnt[ord[d + 1]]) {
            int tswap = ord[d]; ord[d] = ord[d + 1]; ord[d + 1] = tswap;
          }
      #pragma unroll
      for (int a = 0; a < 4; a++) lens[4 + a] = ord[a];
    }
  }
}

// ---------------------------------------------------------------------------
// GEMM main loop (v9, proven 645 TF): VGPR-prefetch + ping-pong LDS double-
// buffer, ONE __syncthreads per K-iter. Prefetch issued at iter i is consumed
// by the ds_write at iter i+1 (a full iteration of latency slack). v10/v11
// variants (global_load_lds; lgkm-only asm barrier) both measured SLOWER
// (barrier-drain with zero slack; regalloc blowup VGPR 76->108). Keep this.
// Requires K >= 64 and K % 32 == 0 (true: K=1024 at all call sites).
// ---------------------------------------------------------------------------
struct TileCtx {
  int m16, quad, wr, wc;
};

DEV void gemm_mainloop(const u16* __restrict__ A, const u16* __restrict__ Bm,
                       int row0, int col0, int K, u16* As, u16* Bs,
                       const TileCtx& t, floatx4 (&acc)[4][4]) {
  int tid = threadIdx.x;
  int wave = tid >> 6, lane = tid & 63;
  int srow = wave * 16 + (lane >> 2);     // 0..63; rounds: srow, srow+64
  int sseg = (lane & 3) * 8;
  const u16* ga = A + (size_t)(row0 + srow) * K + sseg;
  const u16* gb = Bm + (size_t)(col0 + srow) * K + sseg;
  const size_t rstep = (size_t)64 * K;
  int woff = srow * 32 + sseg;

  // tile 0 -> buf0
  uintx4 a0 = *(const uintx4*)ga;
  uintx4 a1 = *(const uintx4*)(ga + rstep);
  uintx4 b0 = *(const uintx4*)gb;
  uintx4 b1 = *(const uintx4*)(gb + rstep);
  *(uintx4*)(As + woff) = a0;
  *(uintx4*)(As + woff + 2048) = a1;
  *(uintx4*)(Bs + woff) = b0;
  *(uintx4*)(Bs + woff + 2048) = b1;
  // prefetch tile 1
  a0 = *(const uintx4*)(ga + 32);
  a1 = *(const uintx4*)(ga + rstep + 32);
  b0 = *(const uintx4*)(gb + 32);
  b1 = *(const uintx4*)(gb + rstep + 32);
  __syncthreads();

  for (int k0 = 0; k0 < K; k0 += 32) {
    int cur = (k0 >> 5) & 1;
    const u16* rA = As + cur * 4096;
    const u16* rB = Bs + cur * 4096;
    bf16x8 af[4], bfr[4];
    #pragma unroll
    for (int i = 0; i < 4; i++)
      af[i] = ld_frag(&rA[(t.wr * 64 + i * 16 + t.m16) * 32 + t.quad * 8]);
    #pragma unroll
    for (int j = 0; j < 4; j++)
      bfr[j] = ld_frag(&rB[(t.wc * 64 + j * 16 + t.m16) * 32 + t.quad * 8]);
    if (k0 + 32 < K) {                    // stage next tile into other buffer
      u16* nA = As + (cur ^ 1) * 4096 + woff;
      u16* nB = Bs + (cur ^ 1) * 4096 + woff;
      *(uintx4*)nA = a0;
      *(uintx4*)(nA + 2048) = a1;
      *(uintx4*)nB = b0;
      *(uintx4*)(nB + 2048) = b1;
      if (k0 + 64 < K) {                  // prefetch tile k0+64
        a0 = *(const uintx4*)(ga + k0 + 64);
        a1 = *(const uintx4*)(ga + rstep + k0 + 64);
        b0 = *(const uintx4*)(gb + k0 + 64);
        b1 = *(const uintx4*)(gb + rstep + k0 + 64);
      }
    }
    #pragma unroll
    for (int i = 0; i < 4; i++)
      #pragma unroll
      for (int j = 0; j < 4; j++)
        acc[i][j] = mfma16(af[i], bfr[j], acc[i][j]);
    __syncthreads();
  }
}

// ---------------------------------------------------------------------------
// Fused Q-proj + KV-proj in ONE launch (1280 blocks), XCD-swizzled:
// consecutive pre-swizzle bids are the col-tiles of one A-row-panel, and
// dispatch round-robins bid%8 across XCDs -> every A-panel was fetched by
// all 8 per-XCD L2s (measured FETCH 104.5 MB vs ~30 ideal). Bijective chunk
// swizzle (1280 % 8 == 0): XCD x gets contiguous bids [x*160, x*160+160) ->
// each A-panel lives on 1 XCD.
//  blocks [0,256):    Q-proj -> qhb bf16 [B,LQ,H,64], x(0.125*log2e)
//  blocks [256,1280): KV-proj -> K [b][h][kv][64], V^T [b][h][d][LKV]
// ---------------------------------------------------------------------------
__global__ __launch_bounds__(256) void proj_fused(
    const u16* __restrict__ qn, const u16* __restrict__ wqb,
    const float* __restrict__ bq, u16* __restrict__ qhb,
    const u16* __restrict__ kvn, const u16* __restrict__ wkvb,
    const float* __restrict__ bkv, u16* __restrict__ khb,
    u16* __restrict__ vthb) {
  __shared__ __align__(16) u16 As[2 * 128 * 32];
  __shared__ __align__(16) u16 Bs[2 * 128 * 32];
  int bid0 = blockIdx.x;
  int bid = (bid0 & 7) * 160 + (bid0 >> 3);   // XCD-contiguous chunks
  int lane = threadIdx.x & 63;
  TileCtx t;
  t.m16 = lane & 15; t.quad = lane >> 4;
  int wave = threadIdx.x >> 6;
  t.wr = wave >> 1; t.wc = wave & 1;

  bool isQ = bid < 256;
  int row0, col0;
  const u16* A; const u16* Bm; const float* bias;
  if (isQ) {
    row0 = (bid >> 3) * 128; col0 = (bid & 7) * 128;
    A = qn; Bm = wqb; bias = bq;
  } else {
    int b2 = bid - 256;
    row0 = (b2 >> 4) * 128; col0 = (b2 & 15) * 128;
    A = kvn; Bm = wkvb; bias = bkv;
  }

  floatx4 z = {0.f, 0.f, 0.f, 0.f};
  floatx4 acc[4][4];
  #pragma unroll
  for (int i = 0; i < 4; i++)
    #pragma unroll
    for (int j = 0; j < 4; j++) acc[i][j] = z;

  gemm_mainloop(A, Bm, row0, col0, cD, As, Bs, t, acc);

  // epilogue: C/D layout col=lane&15, row=quad*4+reg
  #pragma unroll
  for (int j = 0; j < 4; j++) {
    int col = col0 + t.wc * 64 + j * 16 + t.m16;
    float bs = bias[col];
    if (isQ) {
      #pragma unroll
      for (int i = 0; i < 4; i++) {
        int crow = row0 + t.wr * 64 + i * 16 + t.quad * 4;
        #pragma unroll
        for (int r = 0; r < 4; r++)
          qhb[(size_t)(crow + r) * cD + col] =
              f2bf((acc[i][j][r] + bs) * 0.18033688f);   // 0.125 * log2(e)
      }
    } else {
      bool isK = col < cD;
      int c2 = isK ? col : col - cD;
      int hh = c2 >> 6, dd = c2 & 63;
      #pragma unroll
      for (int i = 0; i < 4; i++) {
        int crow = row0 + t.wr * 64 + i * 16 + t.quad * 4;
        int bb = crow >> 11, kvp = crow & (cLKV - 1);
        if (isK) {
          u16* dst = khb + ((size_t)(bb * cH + hh) * cLKV + kvp) * 64 + dd;
          #pragma unroll
          for (int r = 0; r < 4; r++) dst[(size_t)r * 64] = f2bf(acc[i][j][r] + bs);
        } else {
          u16* dst = vthb + ((size_t)(bb * cH + hh) * 64 + dd) * cLKV + kvp;
          ushort4 o;
          o.x = f2bf(acc[i][j][0] + bs);
          o.y = f2bf(acc[i][j][1] + bs);
          o.z = f2bf(acc[i][j][2] + bs);
          o.w = f2bf(acc[i][j][3] + bs);
          *(ushort4*)dst = o;
        }
      }
    }
  }
}

// ---------------------------------------------------------------------------
// O-proj: C f32 = aob @ Wo^T + bo + residual. 1D grid 256, XCD-swizzled
// (256 % 8 == 0): each XCD gets 32 contiguous tiles = 4 full A-row-panels.
// ---------------------------------------------------------------------------
__global__ __launch_bounds__(256) void gemm_o(
    const u16* __restrict__ A, const u16* __restrict__ Bm,
    const float* __restrict__ bias, const float* __restrict__ res,
    float* __restrict__ Cout, int N, int K) {
  __shared__ __align__(16) u16 As[2 * 128 * 32];
  __shared__ __align__(16) u16 Bs[2 * 128 * 32];
  int bid0 = blockIdx.x;
  int swz = (bid0 & 7) * 32 + (bid0 >> 3);
  int row0 = (swz >> 3) * 128, col0 = (swz & 7) * 128;
  int lane = threadIdx.x & 63;
  TileCtx t;
  t.m16 = lane & 15; t.quad = lane >> 4;
  int wave = threadIdx.x >> 6;
  t.wr = wave >> 1; t.wc = wave & 1;

  floatx4 z = {0.f, 0.f, 0.f, 0.f};
  floatx4 acc[4][4];
  #pragma unroll
  for (int i = 0; i < 4; i++)
    #pragma unroll
    for (int j = 0; j < 4; j++) acc[i][j] = z;

  gemm_mainloop(A, Bm, row0, col0, K, As, Bs, t, acc);

  #pragma unroll
  for (int j = 0; j < 4; j++) {
    int col = col0 + t.wc * 64 + j * 16 + t.m16;
    float bs = bias[col];
    #pragma unroll
    for (int i = 0; i < 4; i++) {
      int crow = row0 + t.wr * 64 + i * 16 + t.quad * 4;
      #pragma unroll
      for (int r = 0; r < 4; r++) {
        size_t idx = (size_t)(crow + r) * N + col;
        Cout[idx] = acc[i][j][r] + bs + res[idx];
      }
    }
  }
}

// ---------------------------------------------------------------------------
// Flash cross-attention v12: LDS-THROUGHPUT attack. Arithmetic from v9's
// counters: per chunk-block the LDS pipe moves ~112 KB (~1300 cy at 85 B/cy)
// vs ~310 cy of MFMA -> MfmaUtil 12.6% because the kernel is LDS-bound, and
// K/V fragment read traffic is invariant in q-rows-per-wave. Fix: 32 q-rows
// per wave (two 16-q groups, layout identical to the correctness-validated
// v8 kernel): kf/bv fragments are loaded ONCE and feed BOTH groups' MFMAs ->
// LDS bytes per q-row drop 1.75x. 512 blocks (128 q-rows each), 4 waves,
// v9's proven 2-barrier staged skeleton + VGPR chunk prefetch.
// Tail control at 2 blocks/CU: blocks bid and bid+256 land on the same CU
// (round-robin heuristic), so batch rank map {0,1,3,2} over bid>>7 pairs
// longest-with-shortest and 2nd-with-3rd on each CU.
// LDS = 9216 (K) + 9216 (V) + 18432 (P) = 36864 B.
// ---------------------------------------------------------------------------
constexpr int KS = 72;   // K/V LDS row stride (u16): 144 B, 16B-aligned
constexpr int PS = 72;   // P  LDS row stride (u16)

template<bool MASK>
DEV void attn_compute(int k0, int len, const u16* __restrict__ Kt,
                      const u16* __restrict__ Vt, u16* __restrict__ psw,
                      const bf16x8 (&qf)[2][2], int m16, int quad,
                      float (&lsum)[2], floatx4 (&accO)[2][4]) {
  floatx4 z = {0.f, 0.f, 0.f, 0.f};
  // K fragments loaded ONCE, used by both q-groups.
  // QK^T swapped: A = K (row = kv = t*16+m16, k = d), B = Q (col = q)
  bf16x8 kf[4][2];
  #pragma unroll
  for (int t = 0; t < 4; t++) {
    kf[t][0] = ld_frag(&Kt[(t * 16 + m16) * KS + quad * 8]);
    kf[t][1] = ld_frag(&Kt[(t * 16 + m16) * KS + 32 + quad * 8]);
  }
  floatx4 s[2][4];
  #pragma unroll
  for (int g = 0; g < 2; g++)
    #pragma unroll
    for (int t = 0; t < 4; t++) {
      floatx4 tt = z;
      tt = mfma16(kf[t][0], qf[g][0], tt);
      tt = mfma16(kf[t][1], qf[g][1], tt);
      s[g][t] = tt;
    }
  // exp2 + packed 8-B P-write: lane's 4 regs are CONSECUTIVE kv for its q
  #pragma unroll
  for (int g = 0; g < 2; g++)
    #pragma unroll
    for (int t = 0; t < 4; t++) {
      float e0, e1, e2, e3;
      if (MASK) {
        int key = k0 + t * 16 + quad * 4;
        e0 = (key     < len) ? ex2(s[g][t][0]) : 0.f;
        e1 = (key + 1 < len) ? ex2(s[g][t][1]) : 0.f;
        e2 = (key + 2 < len) ? ex2(s[g][t][2]) : 0.f;
        e3 = (key + 3 < len) ? ex2(s[g][t][3]) : 0.f;
      } else {
        e0 = ex2(s[g][t][0]);
        e1 = ex2(s[g][t][1]);
        e2 = ex2(s[g][t][2]);
        e3 = ex2(s[g][t][3]);
      }
      lsum[g] += (e0 + e1) + (e2 + e3);
      ushort4 pk;
      pk.x = f2bf_t(e0); pk.y = f2bf_t(e1); pk.z = f2bf_t(e2); pk.w = f2bf_t(e3);
      *(ushort4*)&psw[(g * 16 + m16) * PS + t * 16 + quad * 4] = pk;
    }
  // PV: A = P (row = q, k = kv), B = V (col = d); bv loaded once for both
  // groups. Same-wave DS ordering (psw is wave-private) -> no barrier.
  bf16x8 ap0[2], ap1[2];
  #pragma unroll
  for (int g = 0; g < 2; g++) {
    ap0[g] = ld_frag(&psw[(g * 16 + m16) * PS + quad * 8]);
    ap1[g] = ld_frag(&psw[(g * 16 + m16) * PS + 32 + quad * 8]);
  }
  #pragma unroll
  for (int db = 0; db < 4; db++) {
    bf16x8 bv0 = ld_frag(&Vt[(db * 16 + m16) * KS + quad * 8]);
    bf16x8 bv1 = ld_frag(&Vt[(db * 16 + m16) * KS + 32 + quad * 8]);
    #pragma unroll
    for (int g = 0; g < 2; g++) {
      accO[g][db] = mfma16(ap0[g], bv0, accO[g][db]);
      accO[g][db] = mfma16(ap1[g], bv1, accO[g][db]);
    }
  }
}

__global__ __launch_bounds__(256) void attn_kernel(
    const u16* __restrict__ qh, const u16* __restrict__ kh,
    const u16* __restrict__ vth, const int* __restrict__ lens,
    u16* __restrict__ out) {
  int bid = blockIdx.x;                   // 0..511
  int r = bid >> 7;                       // 0..3
  int rank = r ^ (r >> 1);                // {0,1,3,2}: pair long+short per CU
  int b = lens[4 + rank];
  int combo = bid & 127;
  int h = combo >> 3;                     // 0..15
  int qt = combo & 7;                     // 0..7 (128 q-rows per block)
  int len = lens[b];
  int wave = threadIdx.x >> 6, lane = threadIdx.x & 63;
  int m16 = lane & 15, quad = lane >> 4;

  __shared__ __align__(16) u16 Kt[64 * KS];
  __shared__ __align__(16) u16 Vt[64 * KS];
  __shared__ __align__(16) u16 Ps[4][32 * PS];
  u16* psw = &Ps[wave][0];

  // Q as B-operand: two 16-q groups per wave; col = q, k = d
  int q0 = qt * 128 + wave * 32;
  const u16* qp = qh + ((size_t)(b * cLQ + q0 + m16) * cH + h) * cHD;
  bf16x8 qf[2][2];
  qf[0][0] = ld_frag(qp + quad * 8);
  qf[0][1] = ld_frag(qp + 32 + quad * 8);
  qf[1][0] = ld_frag(qp + (size_t)16 * cD + quad * 8);
  qf[1][1] = ld_frag(qp + (size_t)16 * cD + 32 + quad * 8);

  const u16* kbase = kh + (size_t)(b * cH + h) * cLKV * cHD;
  const u16* vbase = vth + (size_t)(b * cH + h) * cHD * cLKV;

  int srow = threadIdx.x >> 3;   // 0..31
  int sseg = threadIdx.x & 7;    // 0..7 (16B segment)
  const u16* kg = kbase + (size_t)srow * cHD + sseg * 8;
  const u16* vg = vbase + (size_t)srow * cLKV + sseg * 8;

  float lsum[2] = {0.f, 0.f};
  floatx4 z = {0.f, 0.f, 0.f, 0.f};
  floatx4 accO[2][4] = {{z, z, z, z}, {z, z, z, z}};

  int nch = (len + 63) >> 6;
  // prefetch chunk 0
  uintx4 ka  = *(const uintx4*)kg;
  uintx4 kb2 = *(const uintx4*)(kg + (size_t)32 * cHD);
  uintx4 va  = *(const uintx4*)vg;
  uintx4 vb  = *(const uintx4*)(vg + (size_t)32 * cLKV);

  for (int c = 0; c < nch; c++) {
    int k0 = c * 64;
    __syncthreads();
    *(uintx4*)&Kt[srow * KS + sseg * 8] = ka;
    *(uintx4*)&Kt[(srow + 32) * KS + sseg * 8] = kb2;
    *(uintx4*)&Vt[srow * KS + sseg * 8] = va;
    *(uintx4*)&Vt[(srow + 32) * KS + sseg * 8] = vb;
    if (c + 1 < nch) {
      int kn = k0 + 64;
      ka  = *(const uintx4*)(kg + (size_t)kn * cHD);
      kb2 = *(const uintx4*)(kg + (size_t)(kn + 32) * cHD);
      va  = *(const uintx4*)(vg + kn);
      vb  = *(const uintx4*)(vg + (size_t)32 * cLKV + kn);
    }
    __syncthreads();
    if (k0 + 64 <= len)
      attn_compute<false>(k0, len, Kt, Vt, psw, qf, m16, quad, lsum, accO);
    else
      attn_compute<true>(k0, len, Kt, Vt, psw, qf, m16, quad, lsum, accO);
  }

  // softmax denominators per group: lane owns q = g*16+m16; reduce quads
  #pragma unroll
  for (int g = 0; g < 2; g++) {
    float tsum = lsum[g];
    tsum += __shfl_xor(tsum, 16, 64);
    tsum += __shfl_xor(tsum, 32, 64);
    #pragma unroll
    for (int rr = 0; rr < 4; rr++) {
      float inv = 1.0f / __shfl(tsum, quad * 4 + rr, 16);
      int qg = q0 + g * 16 + quad * 4 + rr;
      size_t base = ((size_t)(b * cLQ + qg) * cH + h) * cHD;
      #pragma unroll
      for (int db = 0; db < 4; db++)
        out[base + db * 16 + m16] = f2bf(accO[g][db][rr] * inv);
    }
  }
}

// ---------------------------------------------------------------------------
extern "C" void kernel_launch(void* const* d_in, const int* in_sizes, int n_in,
                              void* d_out, int out_size, void* d_ws, size_t ws_size,
                              hipStream_t stream) {
  const float* q    = (const float*)d_in[0];
  const float* kv   = (const float*)d_in[1];
  const void*  mask = d_in[2];
  const float* nqw  = (const float*)d_in[3];
  const float* nqb  = (const float*)d_in[4];
  const float* nkw  = (const float*)d_in[5];
  const float* nkb  = (const float*)d_in[6];
  const float* Wq   = (const float*)d_in[7];
  const float* bq   = (const float*)d_in[8];
  const float* Wkv  = (const float*)d_in[9];
  const float* bkv  = (const float*)d_in[10];
  const float* Wo   = (const float*)d_in[11];
  const float* bo   = (const float*)d_in[12];
  float* out = (float*)d_out;

  char* w = (char*)d_ws;
  int* lens = (int*)w;       w += 256;
  u16* qn   = (u16*)w;       w += (size_t)cB * cLQ * cD * 2;        // 8 MB
  u16* kvn  = (u16*)w;       w += (size_t)cB * cLKV * cD * 2;       // 16 MB
  u16* wqb  = (u16*)w;       w += (size_t)cD * cD * 2;              // 2 MB
  u16* wkvb = (u16*)w;       w += (size_t)2 * cD * cD * 2;          // 4 MB
  u16* wob  = (u16*)w;       w += (size_t)cD * cD * 2;              // 2 MB
  u16* qhb  = (u16*)w;       w += (size_t)cB * cLQ * cD * 2;        // 8 MB
  u16* khb  = (u16*)w;       w += (size_t)cB * cH * cLKV * cHD * 2; // 16 MB
  u16* vthb = (u16*)w;       w += (size_t)cB * cH * cHD * cLKV * 2; // 16 MB
  u16* aob  = (u16*)w;                                              // 8 MB

  prep_kernel<<<cB * (cLQ + cLKV) + 4096 + 1, 256, 0, stream>>>(
      q, kv, nqw, nqb, nkw, nkb, qn, kvn,
      Wq, Wkv, Wo, wqb, wkvb, wob, mask, lens);
  proj_fused<<<1280, 256, 0, stream>>>(
      qn, wqb, bq, qhb, kvn, wkvb, bkv, khb, vthb);
  attn_kernel<<<512, 256, 0, stream>>>(
      qhb, khb, vthb, lens, aob);
  gemm_o<<<dim3(256), 256, 0, stream>>>(
      aob, wob, bo, q, out, cD, cD);
}